// Round 12
// baseline (293.443 us; speedup 1.0000x reference)
//
#include <hip/hip_runtime.h>
#include <hip/hip_fp16.h>

#define DH 256   // feature dim (D == H == 256)

typedef _Float16 half8 __attribute__((ext_vector_type(8)));
typedef float floatx4 __attribute__((ext_vector_type(4)));

// ---------------------------------------------------------------- setup kernels

// merged: init deg/fill/s (blocks [0,nb)) + W transpose/cast (blocks [nb,nb+128))
__global__ __launch_bounds__(256) void k_init_tw(float* __restrict__ deg,
                                                 int* __restrict__ fill,
                                                 float* __restrict__ s, int n,
                                                 const float* __restrict__ W1,
                                                 _Float16* __restrict__ Wt1,
                                                 const float* __restrict__ W2,
                                                 _Float16* __restrict__ Wt2) {
    __shared__ float t[32][33];
    int nb = (n + 255) / 256;
    int b = blockIdx.x;
    if (b < nb) {
        int i = b * 256 + threadIdx.x;
        if (i < n) { deg[i] = 1.0f; fill[i] = 0; s[i] = 0.f; }
        return;
    }
    b -= nb;                       // 0..127 : [z(1)][y(3)][x(3)]
    const float* W = (b & 64) ? W2 : W1;
    _Float16* Wt = (b & 64) ? Wt2 : Wt1;
    int bx = (b & 7) * 32, by = ((b >> 3) & 7) * 32;
    int tx = threadIdx.x & 31, ty = threadIdx.x >> 5;
#pragma unroll
    for (int r = 0; r < 32; r += 8)
        t[ty + r][tx] = W[(size_t)(by + ty + r) * DH + bx + tx];
    __syncthreads();
#pragma unroll
    for (int r = 0; r < 32; r += 8)
        Wt[(size_t)(bx + ty + r) * DH + by + tx] = (_Float16)t[tx][ty + r];
}

__global__ void k_deg(const int* __restrict__ dst, float* __restrict__ deg, int e) {
    int i = blockIdx.x * blockDim.x + threadIdx.x;
    if (i < e) atomicAdd(&deg[dst[i]], 1.0f);
}

// ---- hierarchical exclusive scan of (int)deg -> row_ptr[0..n]; also dinv ----
__global__ __launch_bounds__(1024) void k_scan1(const float* __restrict__ deg,
                                                float* __restrict__ dinv,
                                                int* __restrict__ row_ptr,
                                                int* __restrict__ part, int n) {
    __shared__ int sd[1024];
    int tid = threadIdx.x;
    int i = blockIdx.x * 1024 + tid;
    float dv = (i < n) ? deg[i] : 1.f;
    if (i < n) dinv[i] = rsqrtf(dv);
    int v = (i < n) ? (int)dv : 0;
    sd[tid] = v;
    __syncthreads();
    for (int off = 1; off < 1024; off <<= 1) {
        int t = (tid >= off) ? sd[tid - off] : 0;
        __syncthreads();
        sd[tid] += t;
        __syncthreads();
    }
    if (i < n) row_ptr[i] = sd[tid] - v;
    if (tid == 1023) part[blockIdx.x] = sd[1023];
}

// single-wave shuffle scan of block totals
__global__ void k_scan2(int* __restrict__ part, int* __restrict__ row_ptr,
                        int nparts, int n) {
    int lane = threadIdx.x & 63;
    int carry = 0;
    for (int base = 0; base < nparts; base += 64) {
        int i = base + lane;
        int v = (i < nparts) ? part[i] : 0;
        int orig = v;
        for (int off = 1; off < 64; off <<= 1) {
            int t = __shfl_up(v, off);
            if (lane >= off) v += t;
        }
        if (i < nparts) part[i] = carry + v - orig;   // exclusive
        int tot = __shfl(v, 63);
        carry += tot;
    }
    if (lane == 0) row_ptr[n] = carry;
}

// phase 3: add block offsets; also write self-loop CSR entry
__global__ __launch_bounds__(1024) void k_scan3(int* __restrict__ row_ptr,
                                                const int* __restrict__ part,
                                                const float* __restrict__ dinv,
                                                int* __restrict__ col,
                                                float* __restrict__ wgt,
                                                int* __restrict__ fill, int n) {
    int i = blockIdx.x * 1024 + threadIdx.x;
    if (i < n) {
        int rp = row_ptr[i] + part[blockIdx.x];
        row_ptr[i] = rp;
        col[rp] = i;
        float d = dinv[i];
        wgt[rp] = d * d;
        fill[i] = 1;
    }
}

__global__ void k_csr(const int* __restrict__ src, const int* __restrict__ dst,
                      const float* __restrict__ dinv, const int* __restrict__ row_ptr,
                      int* __restrict__ fill, int* __restrict__ col,
                      float* __restrict__ wgt, int e) {
    int i = blockIdx.x * blockDim.x + threadIdx.x;
    if (i < e) {
        int s0 = src[i], d0 = dst[i];
        int p = row_ptr[d0] + atomicAdd(&fill[d0], 1);
        col[p] = s0;
        wgt[p] = dinv[s0] * dinv[d0];
    }
}

// cast X f32 -> f16 row-major
__global__ __launch_bounds__(256) void k_xh(const float* __restrict__ x,
                                            _Float16* __restrict__ xh, int elems8) {
    int i = blockIdx.x * blockDim.x + threadIdx.x;
    int stride = gridDim.x * blockDim.x;
    for (int j = i; j < elems8; j += stride) {
        const float* p = x + (size_t)j * 8;
        float4 a = *(const float4*)p;
        float4 b = *(const float4*)(p + 4);
        half8 h;
        h[0] = (_Float16)a.x; h[1] = (_Float16)a.y;
        h[2] = (_Float16)a.z; h[3] = (_Float16)a.w;
        h[4] = (_Float16)b.x; h[5] = (_Float16)b.y;
        h[6] = (_Float16)b.z; h[7] = (_Float16)b.w;
        *(half8*)(xh + (size_t)j * 8) = h;
    }
}

// ---------------------------------------------------------------- gather core
// one WAVE per dst node. Lane q holds col/wgt of edge p0+q (one vector load
// per 64 edges); cols broadcast via shfl; 8 gathers of 512B rows in flight.

__device__ __forceinline__ float4 agg_core(const _Float16* __restrict__ G,
                                           const int* __restrict__ row_ptr,
                                           const int* __restrict__ col,
                                           const float* __restrict__ wgt,
                                           int node, int lane) {
    int p0 = row_ptr[node], p1 = row_ptr[node + 1];
    const _Float16* Gl = G + lane * 4;
    float a0 = 0.f, a1 = 0.f, a2 = 0.f, a3 = 0.f;
    for (int base = p0; base < p1; base += 64) {
        int idx = base + lane;
        int   cl = col[min(idx, p1 - 1)];
        float wl = (idx < p1) ? wgt[idx] : 0.f;
        int cnt = min(p1 - base, 64);
        for (int q0 = 0; q0 < cnt; q0 += 8) {
            uint2 u[8];
            float w[8];
#pragma unroll
            for (int q = 0; q < 8; q++) {
                int c = __shfl(cl, q0 + q);
                w[q] = __shfl(wl, q0 + q);
                u[q] = *(const uint2*)(Gl + (size_t)c * DH);
            }
#pragma unroll
            for (int q = 0; q < 8; q++) {
                float2 fa = __half22float2(*(__half2*)&u[q].x);
                float2 fb = __half22float2(*(__half2*)&u[q].y);
                a0 += w[q] * fa.x;
                a1 += w[q] * fa.y;
                a2 += w[q] * fb.x;
                a3 += w[q] * fb.y;
            }
        }
    }
    return make_float4(a0, a1, a2, a3);
}

// ---------------------------------------------------------------- fused layer
// out = relu( (S . G) @ W + b )   [ + s = out . We  when FINAL ]
// Uses agg(G@W) == (agg G)@W (linearity). Block = 512 thr / 8 waves / 64 nodes.
// Phase 1: wave aggregates 8 nodes into swizzled LDS[64][256] f16.
// Phase 2: W-in-registers MFMA gemm from LDS; bias+relu epilogue.

template <bool FINAL>
__global__ __launch_bounds__(512, 4) void k_fused(const _Float16* __restrict__ G,
                                                  const int* __restrict__ row_ptr,
                                                  const int* __restrict__ col,
                                                  const float* __restrict__ wgt,
                                                  const _Float16* __restrict__ Wt,
                                                  const float* __restrict__ bias,
                                                  const float* __restrict__ We,
                                                  void* __restrict__ Outv,
                                                  float* __restrict__ s, int n) {
    __shared__ _Float16 lds[64 * 256];   // 32KB
    int tid = threadIdx.x;
    int wave = tid >> 6, lane = tid & 63;
    int lm = lane & 15;        // row within 16-row fragment
    int kg = lane >> 4;        // k-group 0..3
    int c0 = wave * 32;        // wave's output-column base
    int tb = blockIdx.x * 64;

    // ---- phase 1: aggregate 8 nodes per wave into LDS (swizzled rows)
#pragma unroll
    for (int i = 0; i < 8; i++) {
        int node = tb + wave * 8 + i;
        if (node < n) {
            int nd = __builtin_amdgcn_readfirstlane(node);
            float4 a = agg_core(G, row_ptr, col, wgt, nd, lane);
            int r = wave * 8 + i;
            __half2 h0 = __float22half2_rn(make_float2(a.x, a.y));
            __half2 h1 = __float22half2_rn(make_float2(a.z, a.w));
            uint2 u;
            u.x = *(unsigned int*)&h0;
            u.y = *(unsigned int*)&h1;
            int g = lane >> 1;                       // 16B granule index 0..31
            *(uint2*)(lds + r * 256 + ((g ^ (r & 7)) * 8) + (lane & 1) * 4) = u;
        }
    }

    // W fragments (loaded after the gather to keep gather-phase VGPRs low)
    half8 wfrag[2][8];
#pragma unroll
    for (int jj = 0; jj < 2; jj++)
#pragma unroll
        for (int ss = 0; ss < 8; ss++)
            wfrag[jj][ss] = *(const half8*)(Wt + (size_t)(c0 + jj * 16 + lm) * DH + ss * 32 + kg * 8);

    __syncthreads();

    // ---- phase 2: gemm from LDS
    int rxor = lm & 7;
#pragma unroll
    for (int rf = 0; rf < 4; rf++) {
        floatx4 a0 = {0.f, 0.f, 0.f, 0.f};
        floatx4 a1 = {0.f, 0.f, 0.f, 0.f};
        const _Float16* lrow = lds + (rf * 16 + lm) * 256;
#pragma unroll
        for (int ss = 0; ss < 8; ss++) {
            half8 b = *(const half8*)(lrow + (((ss * 4 + kg) ^ rxor) * 8));
            a0 = __builtin_amdgcn_mfma_f32_16x16x32_f16(wfrag[0][ss], b, a0, 0, 0, 0);
            a1 = __builtin_amdgcn_mfma_f32_16x16x32_f16(wfrag[1][ss], b, a1, 0, 0, 0);
        }
        int m = tb + rf * 16 + lm;
        float d = 0.f;
        if (m < n) {
            int f0 = c0 + kg * 4;
            float4 b40 = *(const float4*)&bias[f0];
            float4 b41 = *(const float4*)&bias[f0 + 16];
            float4 v0 = make_float4(fmaxf(a0[0] + b40.x, 0.f), fmaxf(a0[1] + b40.y, 0.f),
                                    fmaxf(a0[2] + b40.z, 0.f), fmaxf(a0[3] + b40.w, 0.f));
            float4 v1 = make_float4(fmaxf(a1[0] + b41.x, 0.f), fmaxf(a1[1] + b41.y, 0.f),
                                    fmaxf(a1[2] + b41.z, 0.f), fmaxf(a1[3] + b41.w, 0.f));
            if (FINAL) {
                float* orow = (float*)Outv + (size_t)m * DH + f0;
                *(float4*)orow = v0;
                *(float4*)(orow + 16) = v1;
                float4 w0 = *(const float4*)&We[f0];
                float4 w1 = *(const float4*)&We[f0 + 16];
                d = v0.x * w0.x + v0.y * w0.y + v0.z * w0.z + v0.w * w0.w
                  + v1.x * w1.x + v1.y * w1.y + v1.z * w1.z + v1.w * w1.w;
            } else {
                _Float16* orow = (_Float16*)Outv + (size_t)m * DH + f0;
                __half2 h0 = __float22half2_rn(make_float2(v0.x, v0.y));
                __half2 h1 = __float22half2_rn(make_float2(v0.z, v0.w));
                uint2 u;
                u.x = *(unsigned int*)&h0; u.y = *(unsigned int*)&h1;
                *(uint2*)orow = u;
                h0 = __float22half2_rn(make_float2(v1.x, v1.y));
                h1 = __float22half2_rn(make_float2(v1.z, v1.w));
                u.x = *(unsigned int*)&h0; u.y = *(unsigned int*)&h1;
                *(uint2*)(orow + 16) = u;
            }
        }
        if (FINAL) {
            d += __shfl_xor(d, 16);
            d += __shfl_xor(d, 32);
            if (kg == 0 && m < n) atomicAdd(&s[m], d);
        }
    }
}

// ---------------------------------------------------------------- edge output

__global__ void k_y(const int* __restrict__ src, const int* __restrict__ dst,
                    const float* __restrict__ s, const float* __restrict__ be,
                    float* __restrict__ y, int e) {
    int i = blockIdx.x * blockDim.x + threadIdx.x;
    if (i < e) y[i] = 0.5f * (s[src[i]] + s[dst[i]]) + be[0];
}

// ---------------------------------------------------------------- launch

extern "C" void kernel_launch(void* const* d_in, const int* in_sizes, int n_in,
                              void* d_out, int out_size, void* d_ws, size_t ws_size,
                              hipStream_t stream) {
    const float* x  = (const float*)d_in[0];
    const int*   ei = (const int*)d_in[1];
    const float* W1 = (const float*)d_in[2];
    const float* b1 = (const float*)d_in[3];
    const float* W2 = (const float*)d_in[4];
    const float* b2 = (const float*)d_in[5];
    const float* We = (const float*)d_in[6];
    const float* be = (const float*)d_in[7];

    int n = in_sizes[0] / DH;
    int e = in_sizes[1] / 2;
    const int* src = ei;
    const int* dst = ei + e;

    float* out_h = (float*)d_out;                   // n*DH f32 (final)
    float* out_y = out_h + (size_t)n * DH;          // e
    // Xh (f16 cast of x) lives in the out_h region until fused2 overwrites it.
    _Float16* Xh = (_Float16*)d_out;

    char* w = (char*)d_ws;
    _Float16* h1  = (_Float16*)w;  w += ((size_t)n * DH * 2 + 255) & ~255ull;
    _Float16* Wt1 = (_Float16*)w;  w += (size_t)DH * DH * 2;
    _Float16* Wt2 = (_Float16*)w;  w += (size_t)DH * DH * 2;
    float* deg    = (float*)w;  w += (size_t)n * 4;
    float* dinv   = (float*)w;  w += (size_t)n * 4;
    int*   row_ptr= (int*)w;    w += (size_t)(n + 1) * 4;
    int*   fill   = (int*)w;    w += (size_t)n * 4;
    int*   col    = (int*)w;    w += (size_t)(e + n + 64) * 4;   // +pad for clamp reads
    float* wgt    = (float*)w;  w += (size_t)(e + n + 64) * 4;   // +pad
    float* sbuf   = (float*)w;  w += (size_t)n * 4;
    int*   part   = (int*)w;    w += 4096;

    const int tb = 256;
    int nscan = (n + 1023) / 1024;
    int nb_init = (n + 255) / 256;
    k_init_tw<<<nb_init + 128, 256, 0, stream>>>(deg, fill, sbuf, n, W1, Wt1, W2, Wt2);
    k_deg<<<(e + tb - 1) / tb, tb, 0, stream>>>(dst, deg, e);
    k_scan1<<<nscan, 1024, 0, stream>>>(deg, dinv, row_ptr, part, n);
    k_scan2<<<1, 64, 0, stream>>>(part, row_ptr, nscan, n);
    k_scan3<<<nscan, 1024, 0, stream>>>(row_ptr, part, dinv, col, wgt, fill, n);
    k_csr<<<(e + tb - 1) / tb, tb, 0, stream>>>(src, dst, dinv, row_ptr, fill, col, wgt, e);
    k_xh<<<2048, 256, 0, stream>>>(x, Xh, (n * DH) / 8);

    int nblk = (n + 63) / 64;
    k_fused<false><<<nblk, 512, 0, stream>>>(Xh, row_ptr, col, wgt, Wt1, b1, nullptr,
                                             h1, nullptr, n);          // h1 = relu((S.x)W1+b1), f16
    k_fused<true><<<nblk, 512, 0, stream>>>(h1, row_ptr, col, wgt, Wt2, b2, We,
                                            out_h, sbuf, n);           // h + s
    k_y<<<(e + tb - 1) / tb, tb, 0, stream>>>(src, dst, sbuf, be, out_y, e);
}